// Round 2
// baseline (336.928 us; speedup 1.0000x reference)
//
#include <hip/hip_runtime.h>

typedef __attribute__((ext_vector_type(4))) float f32x4;
typedef __attribute__((ext_vector_type(8))) short s16x8;
typedef __attribute__((ext_vector_type(8))) unsigned short u16x8;

#define IN_F 512
#define OUT_F 512
#define STYLE_F 256

__device__ __forceinline__ unsigned short f2bf(float f) {
    unsigned int u = __builtin_bit_cast(unsigned int, f);
    u += 0x7FFFu + ((u >> 16) & 1u);   // round-to-nearest-even
    return (unsigned short)(u >> 16);
}

// ---------------- prep: alpha/beta GEMVs + weight -> bf16 fragment order ----
// wfrag element index = (((ks*32 + nf)*64 + lane)*8 + e)
//   holds weight[n = nf*16 + (lane&15)][k = ks*32 + (lane>>4)*8 + e]
__global__ __launch_bounds__(256) void prep_kernel(
    const float* __restrict__ z,
    const float* __restrict__ weight,
    const float* __restrict__ w_alpha,
    const float* __restrict__ b_alpha,
    const float* __restrict__ w_beta,
    const float* __restrict__ b_beta,
    unsigned short* __restrict__ wfrag,
    float* __restrict__ alpha,
    float* __restrict__ beta)
{
    int gid = blockIdx.x * 256 + threadIdx.x;

    // weight conversion: 4 elements per thread (covers 512*512 exactly)
    int f  = gid << 2;
    int e0 = f & 7;                 // 0 or 4
    int l  = (f >> 3) & 63;
    int nf = (f >> 9) & 31;
    int ks = f >> 14;               // 0..15
    int n  = nf * 16 + (l & 15);
    int k  = ks * 32 + ((l >> 4) << 3) + e0;
    float4 wv = *reinterpret_cast<const float4*>(weight + n * IN_F + k);
    ushort4 o;
    o.x = f2bf(wv.x); o.y = f2bf(wv.y); o.z = f2bf(wv.z); o.w = f2bf(wv.w);
    *reinterpret_cast<ushort4*>(wfrag + f) = o;

    // alpha/beta: 2048 dot products of length 256
    if (gid < 2048) {
        int t = gid & 1023;
        int b = t >> 9;
        int i = t & 511;
        const float* zr = z + b * STYLE_F;
        const float* wr = (gid < 1024 ? w_alpha : w_beta) + i * STYLE_F;
        float acc = 0.f;
        #pragma unroll 4
        for (int kk = 0; kk < STYLE_F; kk += 4) {
            float4 zv = *reinterpret_cast<const float4*>(zr + kk);
            float4 vv = *reinterpret_cast<const float4*>(wr + kk);
            acc += zv.x * vv.x + zv.y * vv.y + zv.z * vv.z + zv.w * vv.w;
        }
        if (gid < 1024) alpha[t] = acc + b_alpha[i];
        else            beta[t]  = acc + b_beta[i];
    }
}

// ---------------- main GEMM: out = (x*alpha) @ W^T + beta ------------------
// BM=128, BN=512 (full), BK=64, 512 threads = 8 waves (2M x 4N),
// wave tile 64x128 = 4x8 fragments of 16x16x32 bf16.
__global__ __launch_bounds__(512, 2) void modlin_kernel(
    const float* __restrict__ x,
    const unsigned short* __restrict__ wfrag,
    const float* __restrict__ alpha,
    const float* __restrict__ beta,
    float* __restrict__ out)
{
    __shared__ __align__(16) unsigned short lds[2][128 * 64];

    const int tid = threadIdx.x;
    const int mb  = blockIdx.x;
    const long long row0 = (long long)mb * 128;
    const int b = mb >> 10;          // 131072 rows per batch / 128 = 1024 blocks

    // ---- staging map: thread -> (row, 16-col quad) of the 128x64 fp32 tile
    const int srow = tid >> 2;       // 0..127
    const int q    = tid & 3;        // cols q*16 .. q*16+15
    const float* xs_base = x + (row0 + srow) * IN_F + q * 16;
    const float* al_base = alpha + b * IN_F + q * 16;
    // LDS byte addr of element (row,c): row*128 + ((c>>3) ^ (row&7))*16 + (c&7)*2
    const int wbyte0 = srow * 128 + (((2 * q    ) ^ (srow & 7)) << 4);
    const int wbyte1 = srow * 128 + (((2 * q + 1) ^ (srow & 7)) << 4);

    // ---- wave / fragment map
    const int l  = tid & 63;
    const int w  = tid >> 6;
    const int wm = w >> 2;           // 0..1  (M)
    const int wn = w & 3;            // 0..3  (N)
    const int fr = l & 15;
    const int fq = l >> 4;           // 0..3
    const int arowbase = wm * 64 + fr;

    const unsigned short* bptr = wfrag + ((wn * 8) * 64 + l) * 8;

    f32x4 acc[4][8];
    #pragma unroll
    for (int i = 0; i < 4; i++)
        #pragma unroll
        for (int j = 0; j < 8; j++)
            acc[i][j] = (f32x4){0.f, 0.f, 0.f, 0.f};

    // ---- prologue: stage K-tile 0 into buf 0
    {
        float4 xv[4], av[4];
        #pragma unroll
        for (int u = 0; u < 4; u++) {
            xv[u] = *reinterpret_cast<const float4*>(xs_base + u * 4);
            av[u] = *reinterpret_cast<const float4*>(al_base + u * 4);
        }
        u16x8 h0, h1;
        #pragma unroll
        for (int u = 0; u < 2; u++) {
            h0[u * 4 + 0] = f2bf(xv[u].x * av[u].x);
            h0[u * 4 + 1] = f2bf(xv[u].y * av[u].y);
            h0[u * 4 + 2] = f2bf(xv[u].z * av[u].z);
            h0[u * 4 + 3] = f2bf(xv[u].w * av[u].w);
        }
        #pragma unroll
        for (int u = 2; u < 4; u++) {
            h1[(u - 2) * 4 + 0] = f2bf(xv[u].x * av[u].x);
            h1[(u - 2) * 4 + 1] = f2bf(xv[u].y * av[u].y);
            h1[(u - 2) * 4 + 2] = f2bf(xv[u].z * av[u].z);
            h1[(u - 2) * 4 + 3] = f2bf(xv[u].w * av[u].w);
        }
        char* lb = (char*)&lds[0][0];
        *reinterpret_cast<u16x8*>(lb + wbyte0) = h0;
        *reinterpret_cast<u16x8*>(lb + wbyte1) = h1;
    }

    // ---- K loop: 8 steps of BK=64 (two 16x16x32 k-slices each)
    for (int kt = 0; kt < 8; ++kt) {
        __syncthreads();
        char* cb = (char*)&lds[kt & 1][0];

        s16x8 afr[4];
        // k-slice 0
        #pragma unroll
        for (int mf = 0; mf < 4; mf++) {
            int row  = arowbase + mf * 16;
            int byte = row * 128 + ((fq ^ (row & 7)) << 4);
            afr[mf] = *reinterpret_cast<const s16x8*>(cb + byte);
        }
        const unsigned short* bp0 = bptr + (kt * 2) * 16384;
        #pragma unroll
        for (int nf = 0; nf < 8; nf++) {
            s16x8 bf = *reinterpret_cast<const s16x8*>(bp0 + nf * 512);
            #pragma unroll
            for (int mf = 0; mf < 4; mf++)
                acc[mf][nf] = __builtin_amdgcn_mfma_f32_16x16x32_bf16(
                    afr[mf], bf, acc[mf][nf], 0, 0, 0);
        }

        // issue next-tile global loads mid-compute (latency hides under MFMAs)
        float4 xv[4], av[4];
        if (kt < 7) {
            const float* xs = xs_base + (kt + 1) * 64;
            const float* as = al_base + (kt + 1) * 64;
            #pragma unroll
            for (int u = 0; u < 4; u++) {
                xv[u] = *reinterpret_cast<const float4*>(xs + u * 4);
                av[u] = *reinterpret_cast<const float4*>(as + u * 4);
            }
        }

        // k-slice 1
        #pragma unroll
        for (int mf = 0; mf < 4; mf++) {
            int row  = arowbase + mf * 16;
            int byte = row * 128 + (((4 + fq) ^ (row & 7)) << 4);
            afr[mf] = *reinterpret_cast<const s16x8*>(cb + byte);
        }
        const unsigned short* bp1 = bp0 + 16384;
        #pragma unroll
        for (int nf = 0; nf < 8; nf++) {
            s16x8 bf = *reinterpret_cast<const s16x8*>(bp1 + nf * 512);
            #pragma unroll
            for (int mf = 0; mf < 4; mf++)
                acc[mf][nf] = __builtin_amdgcn_mfma_f32_16x16x32_bf16(
                    afr[mf], bf, acc[mf][nf], 0, 0, 0);
        }

        // write next tile into the other buffer
        if (kt < 7) {
            u16x8 h0, h1;
            #pragma unroll
            for (int u = 0; u < 2; u++) {
                h0[u * 4 + 0] = f2bf(xv[u].x * av[u].x);
                h0[u * 4 + 1] = f2bf(xv[u].y * av[u].y);
                h0[u * 4 + 2] = f2bf(xv[u].z * av[u].z);
                h0[u * 4 + 3] = f2bf(xv[u].w * av[u].w);
            }
            #pragma unroll
            for (int u = 2; u < 4; u++) {
                h1[(u - 2) * 4 + 0] = f2bf(xv[u].x * av[u].x);
                h1[(u - 2) * 4 + 1] = f2bf(xv[u].y * av[u].y);
                h1[(u - 2) * 4 + 2] = f2bf(xv[u].z * av[u].z);
                h1[(u - 2) * 4 + 3] = f2bf(xv[u].w * av[u].w);
            }
            char* nb = (char*)&lds[(kt + 1) & 1][0];
            *reinterpret_cast<u16x8*>(nb + wbyte0) = h0;
            *reinterpret_cast<u16x8*>(nb + wbyte1) = h1;
        }
    }

    // ---- epilogue: add beta, store fp32
    const float* brow = beta + b * OUT_F;
    #pragma unroll
    for (int nf = 0; nf < 8; nf++) {
        int col = wn * 128 + nf * 16 + fr;
        float bv = brow[col];
        #pragma unroll
        for (int mf = 0; mf < 4; mf++) {
            long long r = row0 + wm * 64 + mf * 16 + fq * 4;
            float* op = out + r * OUT_F + col;
            op[0 * OUT_F] = acc[mf][nf][0] + bv;
            op[1 * OUT_F] = acc[mf][nf][1] + bv;
            op[2 * OUT_F] = acc[mf][nf][2] + bv;
            op[3 * OUT_F] = acc[mf][nf][3] + bv;
        }
    }
}

extern "C" void kernel_launch(void* const* d_in, const int* in_sizes, int n_in,
                              void* d_out, int out_size, void* d_ws, size_t ws_size,
                              hipStream_t stream)
{
    const float* x       = (const float*)d_in[0];
    const float* z       = (const float*)d_in[1];
    const float* weight  = (const float*)d_in[2];
    const float* w_alpha = (const float*)d_in[3];
    const float* b_alpha = (const float*)d_in[4];
    const float* w_beta  = (const float*)d_in[5];
    const float* b_beta  = (const float*)d_in[6];
    float* out = (float*)d_out;

    unsigned short* wfrag = (unsigned short*)d_ws;           // 512 KiB
    float* alpha = (float*)((char*)d_ws + 512 * 1024);       // 4 KiB
    float* beta  = alpha + 2 * IN_F;                         // 4 KiB

    prep_kernel<<<256, 256, 0, stream>>>(z, weight, w_alpha, b_alpha,
                                         w_beta, b_beta, wfrag, alpha, beta);
    modlin_kernel<<<2048, 512, 0, stream>>>(x, wfrag, alpha, beta, out);
}